// Round 1
// baseline (1729.300 us; speedup 1.0000x reference)
//
#include <hip/hip_runtime.h>
#include <math.h>

#define BTOK 16384
#define DDIM 1024
#define HDIM 4096
#define NEXP 8
#define MAXT 136   // max m-tiles: 16384/128 + 8 experts

typedef float f32x4 __attribute__((ext_vector_type(4)));
typedef short short8 __attribute__((ext_vector_type(8)));

__device__ __forceinline__ unsigned int bf16r(float f) {
  unsigned int u = __float_as_uint(f);
  return (u + 0x7fffu + ((u >> 16) & 1u)) >> 16;  // RTN-even
}
__device__ __forceinline__ unsigned int pack2(float a, float b) {
  return bf16r(a) | (bf16r(b) << 16);
}
__device__ __forceinline__ float gelu_tanh(float x) {
  float x3 = x * x * x;
  return 0.5f * x * (1.0f + tanhf(0.7978845608028654f * (x + 0.044715f * x3)));
}

// ---------------- gating: fp64 logits, softmax, argmax, counts ----------------
__global__ __launch_bounds__(256) void gate_kernel(
    const float* __restrict__ x, const float* __restrict__ Wg,
    float* __restrict__ gate_out, float* __restrict__ texp_out,
    float* __restrict__ tscore, int* __restrict__ expert_ws,
    int* __restrict__ counts) {
  int wid = threadIdx.x >> 6, lane = threadIdx.x & 63;
  int b = blockIdx.x * 4 + wid;
  const float* xr = x + (size_t)b * DDIM;
  double acc[8];
#pragma unroll
  for (int e = 0; e < 8; ++e) acc[e] = 0.0;
  for (int d = lane; d < DDIM; d += 64) {
    float xv = xr[d];
    const float4* wp = (const float4*)(Wg + (size_t)d * 8);
    float4 w0 = wp[0], w1 = wp[1];
    acc[0] += (double)xv * (double)w0.x;
    acc[1] += (double)xv * (double)w0.y;
    acc[2] += (double)xv * (double)w0.z;
    acc[3] += (double)xv * (double)w0.w;
    acc[4] += (double)xv * (double)w1.x;
    acc[5] += (double)xv * (double)w1.y;
    acc[6] += (double)xv * (double)w1.z;
    acc[7] += (double)xv * (double)w1.w;
  }
#pragma unroll
  for (int off = 32; off > 0; off >>= 1) {
#pragma unroll
    for (int e = 0; e < 8; ++e) acc[e] += __shfl_down(acc[e], off, 64);
  }
  if (lane == 0) {
    double mx = acc[0];
#pragma unroll
    for (int e = 1; e < 8; ++e) mx = acc[e] > mx ? acc[e] : mx;
    double ex[8], s = 0.0;
#pragma unroll
    for (int e = 0; e < 8; ++e) { ex[e] = exp(acc[e] - mx); s += ex[e]; }
    int best = 0;
#pragma unroll
    for (int e = 1; e < 8; ++e) if (acc[e] > acc[best]) best = e;  // first-max semantics
    double inv = 1.0 / s;
#pragma unroll
    for (int e = 0; e < 8; ++e) gate_out[(size_t)b * 8 + e] = (float)(ex[e] * inv);
    texp_out[b] = (float)best;
    tscore[b] = (float)(ex[best] * inv);
    expert_ws[b] = best;
    atomicAdd(&counts[best], 1);
  }
}

__global__ void init_kernel(int* __restrict__ counts) {
  if (threadIdx.x < NEXP) counts[threadIdx.x] = 0;
}

// single-thread scan: offsets, cursors, density, tile worklist
__global__ void scan_kernel(const int* __restrict__ counts, int* __restrict__ offsets,
                            int* __restrict__ cursors, int* __restrict__ tile_e,
                            int* __restrict__ tile_ms, int* __restrict__ total_tiles,
                            float* __restrict__ dens_out) {
  if (threadIdx.x == 0 && blockIdx.x == 0) {
    int off = 0, t = 0;
    for (int e = 0; e < NEXP; ++e) {
      offsets[e] = off;
      cursors[e] = off;
      dens_out[e] = (float)counts[e] / (float)BTOK;
      for (int ms = 0; ms < counts[e]; ms += 128) { tile_e[t] = e; tile_ms[t] = ms; ++t; }
      off += counts[e];
    }
    offsets[NEXP] = off;
    *total_tiles = t;
  }
}

__global__ __launch_bounds__(256) void scatter_kernel(
    const int* __restrict__ expert_ws, int* __restrict__ cursors,
    int* __restrict__ token_list) {
  int b = blockIdx.x * 256 + threadIdx.x;
  int e = expert_ws[b];
  int pos = atomicAdd(&cursors[e], 1);
  token_list[pos] = b;
}

// ---------------- GEMM1: h = gelu(x_gathered @ W1[e] + b1[e]) -> bf16 ----------------
__global__ __launch_bounds__(256) void gemm1_kernel(
    const float* __restrict__ x, const float* __restrict__ W1,
    const float* __restrict__ b1, const int* __restrict__ token_list,
    const int* __restrict__ offsets, const int* __restrict__ tile_e,
    const int* __restrict__ tile_ms, const int* __restrict__ total_tiles,
    unsigned short* __restrict__ hbuf) {
  __shared__ __align__(16) unsigned short ldsA[128 * 40];  // [m][k] pad->40
  __shared__ unsigned int ldsB[16 * 132];                  // [k-pair][n] bf16x2 words

  int t = blockIdx.x;
  if (t >= *total_tiles) return;
  int e = tile_e[t], mstart = tile_ms[t];
  int base = offsets[e], endp = offsets[e + 1];
  int ntile = blockIdx.y;

  int tid = threadIdx.x;
  int lane = tid & 63, wid = tid >> 6;
  int wr = wid & 1, wc = wid >> 1;
  int quad = lane >> 4, l16 = lane & 15;

  const float* aptr[4];
  bool avalid[4];
#pragma unroll
  for (int it = 0; it < 4; ++it) {
    int idx = tid + 256 * it;
    int m = idx >> 3, q = idx & 7;
    int p = base + mstart + m;
    avalid[it] = (p < endp);
    int tok = avalid[it] ? token_list[p] : 0;
    aptr[it] = x + (size_t)tok * DDIM + 4 * q;
  }
  const float* bptr[8];
#pragma unroll
  for (int it = 0; it < 8; ++it) {
    int u = tid + 256 * it;
    int pr = u >> 7, n = u & 127;
    bptr[it] = W1 + (size_t)e * DDIM * HDIM + (size_t)(2 * pr) * HDIM + ntile * 128 + n;
  }

  f32x4 acc[4][4];
#pragma unroll
  for (int i = 0; i < 4; ++i)
#pragma unroll
    for (int j = 0; j < 4; ++j) acc[i][j] = (f32x4)0.0f;

  for (int k0 = 0; k0 < DDIM; k0 += 32) {
#pragma unroll
    for (int it = 0; it < 4; ++it) {
      int idx = tid + 256 * it;
      int m = idx >> 3, q = idx & 7;
      float4 v = make_float4(0.f, 0.f, 0.f, 0.f);
      if (avalid[it]) v = *(const float4*)(aptr[it] + k0);
      *(uint2*)(&ldsA[m * 40 + 4 * q]) = make_uint2(pack2(v.x, v.y), pack2(v.z, v.w));
    }
#pragma unroll
    for (int it = 0; it < 8; ++it) {
      int u = tid + 256 * it;
      int pr = u >> 7, n = u & 127;
      const float* bp = bptr[it] + (size_t)k0 * HDIM;
      ldsB[pr * 132 + n] = pack2(bp[0], bp[HDIM]);
    }
    __syncthreads();
    short8 af[4], bfr[4];
#pragma unroll
    for (int i = 0; i < 4; ++i) {
      int m = wr * 64 + 16 * i + l16;
      af[i] = *(const short8*)(&ldsA[m * 40 + quad * 8]);
    }
#pragma unroll
    for (int j = 0; j < 4; ++j) {
      int n = wc * 64 + 16 * j + l16;
      union { int4 i4; short8 s8; } u;
      u.i4.x = (int)ldsB[(4 * quad + 0) * 132 + n];
      u.i4.y = (int)ldsB[(4 * quad + 1) * 132 + n];
      u.i4.z = (int)ldsB[(4 * quad + 2) * 132 + n];
      u.i4.w = (int)ldsB[(4 * quad + 3) * 132 + n];
      bfr[j] = u.s8;
    }
#pragma unroll
    for (int i = 0; i < 4; ++i)
#pragma unroll
      for (int j = 0; j < 4; ++j)
        acc[i][j] = __builtin_amdgcn_mfma_f32_16x16x32_bf16(af[i], bfr[j], acc[i][j], 0, 0, 0);
    __syncthreads();
  }

  const float* b1e = b1 + (size_t)e * HDIM + ntile * 128;
#pragma unroll
  for (int i = 0; i < 4; ++i) {
#pragma unroll
    for (int r = 0; r < 4; ++r) {
      int row = wr * 64 + 16 * i + quad * 4 + r;
      int p = base + mstart + row;
      if (p < endp) {
#pragma unroll
        for (int j = 0; j < 4; ++j) {
          int col = wc * 64 + 16 * j + l16;
          float v = acc[i][j][r] + b1e[col];
          hbuf[(size_t)p * HDIM + ntile * 128 + col] = (unsigned short)bf16r(gelu_tanh(v));
        }
      }
    }
  }
}

// ---------------- GEMM2: out[tok] = (h @ W2[e] + b2[e]) * top_score ----------------
__global__ __launch_bounds__(256) void gemm2_kernel(
    const unsigned short* __restrict__ hbuf, const float* __restrict__ W2,
    const float* __restrict__ b2, const int* __restrict__ token_list,
    const int* __restrict__ offsets, const int* __restrict__ tile_e,
    const int* __restrict__ tile_ms, const int* __restrict__ total_tiles,
    const float* __restrict__ tscore, float* __restrict__ out) {
  __shared__ __align__(16) unsigned short ldsA[128 * 40];
  __shared__ unsigned int ldsB[16 * 132];

  int t = blockIdx.x;
  if (t >= *total_tiles) return;
  int e = tile_e[t], mstart = tile_ms[t];
  int base = offsets[e], endp = offsets[e + 1];
  int ntile = blockIdx.y;
  int tid = threadIdx.x;
  int lane = tid & 63, wid = tid >> 6;
  int wr = wid & 1, wc = wid >> 1;
  int quad = lane >> 4, l16 = lane & 15;

  const unsigned short* aptr[2];
  bool avalid[2];
#pragma unroll
  for (int it = 0; it < 2; ++it) {
    int u = tid + 256 * it;
    int m = u >> 2, o = u & 3;
    int p = base + mstart + m;
    avalid[it] = (p < endp);
    aptr[it] = hbuf + (size_t)(avalid[it] ? p : 0) * HDIM + 8 * o;
  }
  const float* bptr[8];
#pragma unroll
  for (int it = 0; it < 8; ++it) {
    int u = tid + 256 * it;
    int pr = u >> 7, n = u & 127;
    bptr[it] = W2 + (size_t)e * HDIM * DDIM + (size_t)(2 * pr) * DDIM + ntile * 128 + n;
  }

  f32x4 acc[4][4];
#pragma unroll
  for (int i = 0; i < 4; ++i)
#pragma unroll
    for (int j = 0; j < 4; ++j) acc[i][j] = (f32x4)0.0f;

  for (int k0 = 0; k0 < HDIM; k0 += 32) {
#pragma unroll
    for (int it = 0; it < 2; ++it) {
      int u = tid + 256 * it;
      int m = u >> 2, o = u & 3;
      uint4 v = make_uint4(0u, 0u, 0u, 0u);
      if (avalid[it]) v = *(const uint4*)(aptr[it] + k0);
      *(uint4*)(&ldsA[m * 40 + 8 * o]) = v;
    }
#pragma unroll
    for (int it = 0; it < 8; ++it) {
      int u = tid + 256 * it;
      int pr = u >> 7, n = u & 127;
      const float* bp = bptr[it] + (size_t)k0 * DDIM;
      ldsB[pr * 132 + n] = pack2(bp[0], bp[DDIM]);
    }
    __syncthreads();
    short8 af[4], bfr[4];
#pragma unroll
    for (int i = 0; i < 4; ++i) {
      int m = wr * 64 + 16 * i + l16;
      af[i] = *(const short8*)(&ldsA[m * 40 + quad * 8]);
    }
#pragma unroll
    for (int j = 0; j < 4; ++j) {
      int n = wc * 64 + 16 * j + l16;
      union { int4 i4; short8 s8; } u;
      u.i4.x = (int)ldsB[(4 * quad + 0) * 132 + n];
      u.i4.y = (int)ldsB[(4 * quad + 1) * 132 + n];
      u.i4.z = (int)ldsB[(4 * quad + 2) * 132 + n];
      u.i4.w = (int)ldsB[(4 * quad + 3) * 132 + n];
      bfr[j] = u.s8;
    }
#pragma unroll
    for (int i = 0; i < 4; ++i)
#pragma unroll
      for (int j = 0; j < 4; ++j)
        acc[i][j] = __builtin_amdgcn_mfma_f32_16x16x32_bf16(af[i], bfr[j], acc[i][j], 0, 0, 0);
    __syncthreads();
  }

  const float* b2e = b2 + (size_t)e * DDIM + ntile * 128;
#pragma unroll
  for (int i = 0; i < 4; ++i) {
#pragma unroll
    for (int r = 0; r < 4; ++r) {
      int row = wr * 64 + 16 * i + quad * 4 + r;
      int p = base + mstart + row;
      if (p < endp) {
        int tok = token_list[p];
        float ts = tscore[tok];
#pragma unroll
        for (int j = 0; j < 4; ++j) {
          int col = wc * 64 + 16 * j + l16;
          out[(size_t)tok * DDIM + ntile * 128 + col] = (acc[i][j][r] + b2e[col]) * ts;
        }
      }
    }
  }
}

extern "C" void kernel_launch(void* const* d_in, const int* in_sizes, int n_in,
                              void* d_out, int out_size, void* d_ws, size_t ws_size,
                              hipStream_t stream) {
  const float* x  = (const float*)d_in[0];
  const float* Wg = (const float*)d_in[1];
  const float* W1 = (const float*)d_in[2];
  const float* b1 = (const float*)d_in[3];
  const float* W2 = (const float*)d_in[4];
  const float* b2 = (const float*)d_in[5];

  float* out_main = (float*)d_out;
  float* gate_out = out_main + (size_t)BTOK * DDIM;
  float* texp_out = gate_out + (size_t)BTOK * NEXP;
  float* dens_out = texp_out + BTOK;

  char* w = (char*)d_ws;
  unsigned short* hbuf = (unsigned short*)w;     // B*H bf16 = 128 MiB
  size_t off = (size_t)BTOK * HDIM * 2;
  float* tscore     = (float*)(w + off); off += (size_t)BTOK * 4;
  int* expert_ws    = (int*)(w + off);   off += (size_t)BTOK * 4;
  int* token_list   = (int*)(w + off);   off += (size_t)BTOK * 4;
  int* counts       = (int*)(w + off);   off += 256;
  int* offsets      = (int*)(w + off);   off += 256;
  int* cursors      = (int*)(w + off);   off += 256;
  int* tile_e       = (int*)(w + off);   off += 1024;
  int* tile_ms      = (int*)(w + off);   off += 1024;
  int* total_tiles  = (int*)(w + off);   off += 256;

  hipLaunchKernelGGL(init_kernel, dim3(1), dim3(64), 0, stream, counts);
  hipLaunchKernelGGL(gate_kernel, dim3(BTOK / 4), dim3(256), 0, stream,
                     x, Wg, gate_out, texp_out, tscore, expert_ws, counts);
  hipLaunchKernelGGL(scan_kernel, dim3(1), dim3(1), 0, stream,
                     counts, offsets, cursors, tile_e, tile_ms, total_tiles, dens_out);
  hipLaunchKernelGGL(scatter_kernel, dim3(BTOK / 256), dim3(256), 0, stream,
                     expert_ws, cursors, token_list);
  hipLaunchKernelGGL(gemm1_kernel, dim3(MAXT, HDIM / 128), dim3(256), 0, stream,
                     x, W1, b1, token_list, offsets, tile_e, tile_ms, total_tiles, hbuf);
  hipLaunchKernelGGL(gemm2_kernel, dim3(MAXT, DDIM / 128), dim3(256), 0, stream,
                     hbuf, W2, b2, token_list, offsets, tile_e, tile_ms, total_tiles, tscore, out_main);
}

// Round 2
// 1138.287 us; speedup vs baseline: 1.5192x; 1.5192x over previous
//
#include <hip/hip_runtime.h>
#include <math.h>

#define BTOK 16384
#define DDIM 1024
#define HDIM 4096
#define NEXP 8
#define MAXT 136   // max m-tiles: 16384/128 + 8 experts

typedef float f32x4 __attribute__((ext_vector_type(4)));
typedef short short8 __attribute__((ext_vector_type(8)));

__device__ __forceinline__ unsigned int bf16r(float f) {
  unsigned int u = __float_as_uint(f);
  return (u + 0x7fffu + ((u >> 16) & 1u)) >> 16;  // RTN-even
}
__device__ __forceinline__ unsigned int pack2(float a, float b) {
  return bf16r(a) | (bf16r(b) << 16);
}
__device__ __forceinline__ float gelu_tanh(float x) {
  float x3 = x * x * x;
  return 0.5f * x * (1.0f + tanhf(0.7978845608028654f * (x + 0.044715f * x3)));
}
// async global->LDS, 16B per lane; LDS dest must be uniform base + lane*16
__device__ __forceinline__ void gload16(const void* g, void* l) {
  __builtin_amdgcn_global_load_lds(
      (const __attribute__((address_space(1))) unsigned int*)g,
      (__attribute__((address_space(3))) unsigned int*)l, 16, 0, 0);
}

// ---------------- gating: fp64 logits, softmax, argmax, counts ----------------
__global__ __launch_bounds__(256) void gate_kernel(
    const float* __restrict__ x, const float* __restrict__ Wg,
    float* __restrict__ gate_out, float* __restrict__ texp_out,
    float* __restrict__ tscore, int* __restrict__ expert_ws,
    int* __restrict__ counts) {
  int wid = threadIdx.x >> 6, lane = threadIdx.x & 63;
  int b = blockIdx.x * 4 + wid;
  const float* xr = x + (size_t)b * DDIM;
  double acc[8];
#pragma unroll
  for (int e = 0; e < 8; ++e) acc[e] = 0.0;
  for (int d = lane; d < DDIM; d += 64) {
    float xv = xr[d];
    const float4* wp = (const float4*)(Wg + (size_t)d * 8);
    float4 w0 = wp[0], w1 = wp[1];
    acc[0] += (double)xv * (double)w0.x;
    acc[1] += (double)xv * (double)w0.y;
    acc[2] += (double)xv * (double)w0.z;
    acc[3] += (double)xv * (double)w0.w;
    acc[4] += (double)xv * (double)w1.x;
    acc[5] += (double)xv * (double)w1.y;
    acc[6] += (double)xv * (double)w1.z;
    acc[7] += (double)xv * (double)w1.w;
  }
#pragma unroll
  for (int off = 32; off > 0; off >>= 1) {
#pragma unroll
    for (int e = 0; e < 8; ++e) acc[e] += __shfl_down(acc[e], off, 64);
  }
  if (lane == 0) {
    double mx = acc[0];
#pragma unroll
    for (int e = 1; e < 8; ++e) mx = acc[e] > mx ? acc[e] : mx;
    double ex[8], s = 0.0;
#pragma unroll
    for (int e = 0; e < 8; ++e) { ex[e] = exp(acc[e] - mx); s += ex[e]; }
    int best = 0;
#pragma unroll
    for (int e = 1; e < 8; ++e) if (acc[e] > acc[best]) best = e;  // first-max semantics
    double inv = 1.0 / s;
#pragma unroll
    for (int e = 0; e < 8; ++e) gate_out[(size_t)b * 8 + e] = (float)(ex[e] * inv);
    texp_out[b] = (float)best;
    tscore[b] = (float)(ex[best] * inv);
    expert_ws[b] = best;
    atomicAdd(&counts[best], 1);
  }
}

__global__ void init_kernel(int* __restrict__ counts) {
  if (threadIdx.x < NEXP) counts[threadIdx.x] = 0;
}

// single-thread scan: offsets, cursors, density, tile worklist
__global__ void scan_kernel(const int* __restrict__ counts, int* __restrict__ offsets,
                            int* __restrict__ cursors, int* __restrict__ tile_e,
                            int* __restrict__ tile_ms, int* __restrict__ total_tiles,
                            float* __restrict__ dens_out) {
  if (threadIdx.x == 0 && blockIdx.x == 0) {
    int off = 0, t = 0;
    for (int e = 0; e < NEXP; ++e) {
      offsets[e] = off;
      cursors[e] = off;
      dens_out[e] = (float)counts[e] / (float)BTOK;
      for (int ms = 0; ms < counts[e]; ms += 128) { tile_e[t] = e; tile_ms[t] = ms; ++t; }
      off += counts[e];
    }
    offsets[NEXP] = off;
    *total_tiles = t;
  }
}

__global__ __launch_bounds__(256) void scatter_kernel(
    const int* __restrict__ expert_ws, int* __restrict__ cursors,
    int* __restrict__ token_list) {
  int b = blockIdx.x * 256 + threadIdx.x;
  int e = expert_ws[b];
  int pos = atomicAdd(&cursors[e], 1);
  token_list[pos] = b;
}

// ---------------- conversion: x fp32 -> bf16 ----------------
__global__ __launch_bounds__(256) void cvt_x_kernel(const float* __restrict__ in,
                                                    unsigned short* __restrict__ out) {
  size_t i = ((size_t)blockIdx.x * 256 + threadIdx.x) * 8;
  float4 a = *(const float4*)(in + i);
  float4 b = *(const float4*)(in + i + 4);
  uint4 o = make_uint4(pack2(a.x, a.y), pack2(a.z, a.w), pack2(b.x, b.y), pack2(b.z, b.w));
  *(uint4*)(out + i) = o;
}

// ---------------- transpose + convert: in[z][R][C] fp32 -> out[z][C][R] bf16 ----------------
__global__ __launch_bounds__(256) void transpose_cvt_kernel(
    const float* __restrict__ in, unsigned short* __restrict__ out, int R, int C) {
  __shared__ unsigned int tile[64 * 33];  // 64x64 bf16 tile, 2 per word, pad 33
  const float* ine = in + (size_t)blockIdx.z * R * C;
  unsigned short* oute = out + (size_t)blockIdx.z * R * C;
  int r0 = blockIdx.y * 64, c0 = blockIdx.x * 64;
  int tid = threadIdx.x;
#pragma unroll
  for (int l = 0; l < 4; ++l) {
    int f = tid + 256 * l;          // 0..1023 float4 slots
    int r = f >> 4, c4 = f & 15;    // row, float4-col
    float4 v = *(const float4*)(ine + (size_t)(r0 + r) * C + c0 + c4 * 4);
    tile[r * 33 + c4 * 2]     = pack2(v.x, v.y);
    tile[r * 33 + c4 * 2 + 1] = pack2(v.z, v.w);
  }
  __syncthreads();
  const unsigned short* t16 = (const unsigned short*)tile;
#pragma unroll
  for (int l = 0; l < 4; ++l) {
    int f = tid + 256 * l;          // 0..1023
    int c = f >> 4, rq = f & 15;    // out-row (=col), r-quad
    unsigned short e0 = t16[((4 * rq + 0) * 33 + (c >> 1)) * 2 + (c & 1)];
    unsigned short e1 = t16[((4 * rq + 1) * 33 + (c >> 1)) * 2 + (c & 1)];
    unsigned short e2 = t16[((4 * rq + 2) * 33 + (c >> 1)) * 2 + (c & 1)];
    unsigned short e3 = t16[((4 * rq + 3) * 33 + (c >> 1)) * 2 + (c & 1)];
    uint2 o;
    o.x = (unsigned int)e0 | ((unsigned int)e1 << 16);
    o.y = (unsigned int)e2 | ((unsigned int)e3 << 16);
    *(uint2*)(oute + (size_t)(c0 + c) * R + r0 + rq * 4) = o;
  }
}

// ---------------- GEMM1: h = gelu(x_gathered @ W1[e] + b1[e]) -> bf16 ----------------
// A: xbf rows gathered via token_list; B: W1t [e][n][k] bf16. m97 structure.
__global__ __launch_bounds__(256) void gemm1_kernel(
    const unsigned short* __restrict__ xbf, const unsigned short* __restrict__ W1t,
    const float* __restrict__ b1, const int* __restrict__ token_list,
    const int* __restrict__ offsets, const int* __restrict__ tile_e,
    const int* __restrict__ tile_ms, const int* __restrict__ total_tiles,
    unsigned short* __restrict__ hbuf) {
  __shared__ __align__(16) unsigned short ldsA[128 * 32];
  __shared__ __align__(16) unsigned short ldsB[128 * 32];

  int t = blockIdx.x;
  if (t >= *total_tiles) return;
  int e = tile_e[t], mstart = tile_ms[t];
  int base = offsets[e], endp = offsets[e + 1];
  int ntile = blockIdx.y;

  int tid = threadIdx.x;
  int lane = tid & 63, wid = tid >> 6;
  int wr = wid & 1, wc = wid >> 1;
  int quad = lane >> 4, l16 = lane & 15;

  int rowA = tid >> 2, chunk = tid & 3;
  int p0 = base + mstart + rowA;
  int p1 = p0 + 64;
  int tok0 = token_list[p0 < endp ? p0 : endp - 1];
  int tok1 = token_list[p1 < endp ? p1 : endp - 1];
  const unsigned short* ga0 = xbf + (size_t)tok0 * DDIM + chunk * 8;
  const unsigned short* ga1 = xbf + (size_t)tok1 * DDIM + chunk * 8;
  const unsigned short* gb0 =
      W1t + (size_t)e * HDIM * DDIM + (size_t)(ntile * 128 + rowA) * DDIM + chunk * 8;
  const unsigned short* gb1 = gb0 + (size_t)64 * DDIM;
  unsigned short* la0 = &ldsA[tid * 8];
  unsigned short* la1 = &ldsA[2048 + tid * 8];
  unsigned short* lb0 = &ldsB[tid * 8];
  unsigned short* lb1 = &ldsB[2048 + tid * 8];

  f32x4 acc[4][4];
#pragma unroll
  for (int i = 0; i < 4; ++i)
#pragma unroll
    for (int j = 0; j < 4; ++j) acc[i][j] = (f32x4)0.0f;

  for (int k0 = 0; k0 < DDIM; k0 += 32) {
    gload16(ga0 + k0, la0);
    gload16(ga1 + k0, la1);
    gload16(gb0 + k0, lb0);
    gload16(gb1 + k0, lb1);
    __syncthreads();
    short8 af[4], bfr[4];
#pragma unroll
    for (int i = 0; i < 4; ++i)
      af[i] = *(const short8*)(&ldsA[(wr * 64 + 16 * i + l16) * 32 + quad * 8]);
#pragma unroll
    for (int j = 0; j < 4; ++j)
      bfr[j] = *(const short8*)(&ldsB[(wc * 64 + 16 * j + l16) * 32 + quad * 8]);
#pragma unroll
    for (int i = 0; i < 4; ++i)
#pragma unroll
      for (int j = 0; j < 4; ++j)
        acc[i][j] = __builtin_amdgcn_mfma_f32_16x16x32_bf16(af[i], bfr[j], acc[i][j], 0, 0, 0);
    __syncthreads();
  }

  const float* b1e = b1 + (size_t)e * HDIM + ntile * 128;
#pragma unroll
  for (int i = 0; i < 4; ++i) {
#pragma unroll
    for (int r = 0; r < 4; ++r) {
      int row = wr * 64 + 16 * i + quad * 4 + r;
      int p = base + mstart + row;
      if (p < endp) {
        size_t ob = (size_t)p * HDIM + ntile * 128;
#pragma unroll
        for (int j = 0; j < 4; ++j) {
          int col = wc * 64 + 16 * j + l16;
          float v = acc[i][j][r] + b1e[col];
          hbuf[ob + col] = (unsigned short)bf16r(gelu_tanh(v));
        }
      }
    }
  }
}

// ---------------- GEMM2: out[tok] = (h @ W2[e] + b2[e]) * top_score ----------------
__global__ __launch_bounds__(256) void gemm2_kernel(
    const unsigned short* __restrict__ hbuf, const unsigned short* __restrict__ W2t,
    const float* __restrict__ b2, const int* __restrict__ token_list,
    const int* __restrict__ offsets, const int* __restrict__ tile_e,
    const int* __restrict__ tile_ms, const int* __restrict__ total_tiles,
    const float* __restrict__ tscore, float* __restrict__ out) {
  __shared__ __align__(16) unsigned short ldsA[128 * 32];
  __shared__ __align__(16) unsigned short ldsB[128 * 32];

  int t = blockIdx.x;
  if (t >= *total_tiles) return;
  int e = tile_e[t], mstart = tile_ms[t];
  int base = offsets[e], endp = offsets[e + 1];
  int ntile = blockIdx.y;

  int tid = threadIdx.x;
  int lane = tid & 63, wid = tid >> 6;
  int wr = wid & 1, wc = wid >> 1;
  int quad = lane >> 4, l16 = lane & 15;

  int rowA = tid >> 2, chunk = tid & 3;
  int p0 = base + mstart + rowA;
  int p1 = p0 + 64;
  int pe0 = p0 < endp ? p0 : endp - 1;
  int pe1 = p1 < endp ? p1 : endp - 1;
  const unsigned short* ga0 = hbuf + (size_t)pe0 * HDIM + chunk * 8;
  const unsigned short* ga1 = hbuf + (size_t)pe1 * HDIM + chunk * 8;
  const unsigned short* gb0 =
      W2t + (size_t)e * HDIM * DDIM + (size_t)(ntile * 128 + rowA) * HDIM + chunk * 8;
  const unsigned short* gb1 = gb0 + (size_t)64 * HDIM;
  unsigned short* la0 = &ldsA[tid * 8];
  unsigned short* la1 = &ldsA[2048 + tid * 8];
  unsigned short* lb0 = &ldsB[tid * 8];
  unsigned short* lb1 = &ldsB[2048 + tid * 8];

  f32x4 acc[4][4];
#pragma unroll
  for (int i = 0; i < 4; ++i)
#pragma unroll
    for (int j = 0; j < 4; ++j) acc[i][j] = (f32x4)0.0f;

  for (int k0 = 0; k0 < HDIM; k0 += 32) {
    gload16(ga0 + k0, la0);
    gload16(ga1 + k0, la1);
    gload16(gb0 + k0, lb0);
    gload16(gb1 + k0, lb1);
    __syncthreads();
    short8 af[4], bfr[4];
#pragma unroll
    for (int i = 0; i < 4; ++i)
      af[i] = *(const short8*)(&ldsA[(wr * 64 + 16 * i + l16) * 32 + quad * 8]);
#pragma unroll
    for (int j = 0; j < 4; ++j)
      bfr[j] = *(const short8*)(&ldsB[(wc * 64 + 16 * j + l16) * 32 + quad * 8]);
#pragma unroll
    for (int i = 0; i < 4; ++i)
#pragma unroll
      for (int j = 0; j < 4; ++j)
        acc[i][j] = __builtin_amdgcn_mfma_f32_16x16x32_bf16(af[i], bfr[j], acc[i][j], 0, 0, 0);
    __syncthreads();
  }

  const float* b2e = b2 + (size_t)e * DDIM + ntile * 128;
#pragma unroll
  for (int i = 0; i < 4; ++i) {
#pragma unroll
    for (int r = 0; r < 4; ++r) {
      int row = wr * 64 + 16 * i + quad * 4 + r;
      int p = base + mstart + row;
      if (p < endp) {
        int tok = token_list[p];
        float ts = tscore[tok];
        size_t ob = (size_t)tok * DDIM + ntile * 128;
#pragma unroll
        for (int j = 0; j < 4; ++j) {
          int col = wc * 64 + 16 * j + l16;
          out[ob + col] = (acc[i][j][r] + b2e[col]) * ts;
        }
      }
    }
  }
}

extern "C" void kernel_launch(void* const* d_in, const int* in_sizes, int n_in,
                              void* d_out, int out_size, void* d_ws, size_t ws_size,
                              hipStream_t stream) {
  const float* x  = (const float*)d_in[0];
  const float* Wg = (const float*)d_in[1];
  const float* W1 = (const float*)d_in[2];
  const float* b1 = (const float*)d_in[3];
  const float* W2 = (const float*)d_in[4];
  const float* b2 = (const float*)d_in[5];

  float* out_main = (float*)d_out;
  float* gate_out = out_main + (size_t)BTOK * DDIM;
  float* texp_out = gate_out + (size_t)BTOK * NEXP;
  float* dens_out = texp_out + BTOK;

  char* w = (char*)d_ws;
  size_t off = 0;
  unsigned short* hbuf = (unsigned short*)(w + off); off += (size_t)BTOK * HDIM * 2;  // 134 MB
  unsigned short* xbf  = (unsigned short*)(w + off); off += (size_t)BTOK * DDIM * 2;  // 33.5 MB
  unsigned short* W1t  = (unsigned short*)(w + off); off += (size_t)NEXP * DDIM * HDIM * 2;  // 67 MB
  unsigned short* W2t  = (unsigned short*)(w + off); off += (size_t)NEXP * DDIM * HDIM * 2;  // 67 MB
  float* tscore     = (float*)(w + off); off += (size_t)BTOK * 4;
  int* expert_ws    = (int*)(w + off);   off += (size_t)BTOK * 4;
  int* token_list   = (int*)(w + off);   off += (size_t)BTOK * 4;
  int* counts       = (int*)(w + off);   off += 256;
  int* offsets      = (int*)(w + off);   off += 256;
  int* cursors      = (int*)(w + off);   off += 256;
  int* tile_e       = (int*)(w + off);   off += 1024;
  int* tile_ms      = (int*)(w + off);   off += 1024;
  int* total_tiles  = (int*)(w + off);   off += 256;

  hipLaunchKernelGGL(init_kernel, dim3(1), dim3(64), 0, stream, counts);
  hipLaunchKernelGGL(gate_kernel, dim3(BTOK / 4), dim3(256), 0, stream,
                     x, Wg, gate_out, texp_out, tscore, expert_ws, counts);
  hipLaunchKernelGGL(cvt_x_kernel, dim3(BTOK * DDIM / 2048), dim3(256), 0, stream, x, xbf);
  hipLaunchKernelGGL(transpose_cvt_kernel, dim3(HDIM / 64, DDIM / 64, NEXP), dim3(256), 0, stream,
                     W1, W1t, DDIM, HDIM);
  hipLaunchKernelGGL(transpose_cvt_kernel, dim3(DDIM / 64, HDIM / 64, NEXP), dim3(256), 0, stream,
                     W2, W2t, HDIM, DDIM);
  hipLaunchKernelGGL(scan_kernel, dim3(1), dim3(1), 0, stream,
                     counts, offsets, cursors, tile_e, tile_ms, total_tiles, dens_out);
  hipLaunchKernelGGL(scatter_kernel, dim3(BTOK / 256), dim3(256), 0, stream,
                     expert_ws, cursors, token_list);
  hipLaunchKernelGGL(gemm1_kernel, dim3(MAXT, HDIM / 128), dim3(256), 0, stream,
                     xbf, W1t, b1, token_list, offsets, tile_e, tile_ms, total_tiles, hbuf);
  hipLaunchKernelGGL(gemm2_kernel, dim3(MAXT, DDIM / 128), dim3(256), 0, stream,
                     hbuf, W2t, b2, token_list, offsets, tile_e, tile_ms, total_tiles, tscore, out_main);
}

// Round 3
// 1115.935 us; speedup vs baseline: 1.5496x; 1.0200x over previous
//
#include <hip/hip_runtime.h>
#include <math.h>

#define BTOK 16384
#define DDIM 1024
#define HDIM 4096
#define NEXP 8
#define MAXT 136   // max m-tiles: 16384/128 + 8 experts

typedef float f32x4 __attribute__((ext_vector_type(4)));
typedef short short8 __attribute__((ext_vector_type(8)));

__device__ __forceinline__ unsigned int bf16r(float f) {
  unsigned int u = __float_as_uint(f);
  return (u + 0x7fffu + ((u >> 16) & 1u)) >> 16;  // RTN-even
}
__device__ __forceinline__ unsigned int pack2(float a, float b) {
  return bf16r(a) | (bf16r(b) << 16);
}
// tanh-GELU via exp: x*(1 - 1/(1+e^{2t})), t = sqrt(2/pi)(x+0.044715x^3)
// e=inf -> x*(1-0) = x; e->0 -> x*(1-1) = 0. No NaN paths.
__device__ __forceinline__ float gelu_fast(float x) {
  float t = 0.7978845608028654f * x * (1.0f + 0.044715f * x * x);
  float e = __expf(2.0f * t);
  return x * (1.0f - __builtin_amdgcn_rcpf(e + 1.0f));
}
// async global->LDS, 16B per lane; LDS dest must be uniform base + lane*16
__device__ __forceinline__ void gload16(const void* g, void* l) {
  __builtin_amdgcn_global_load_lds(
      (const __attribute__((address_space(1))) unsigned int*)g,
      (__attribute__((address_space(3))) unsigned int*)l, 16, 0, 0);
}

// ---------------- gating: fp64 logits, softmax, argmax, counts ----------------
__global__ __launch_bounds__(256) void gate_kernel(
    const float* __restrict__ x, const float* __restrict__ Wg,
    float* __restrict__ gate_out, float* __restrict__ texp_out,
    float* __restrict__ tscore, int* __restrict__ expert_ws,
    int* __restrict__ counts) {
  int wid = threadIdx.x >> 6, lane = threadIdx.x & 63;
  int b = blockIdx.x * 4 + wid;
  const float* xr = x + (size_t)b * DDIM;
  double acc[8];
#pragma unroll
  for (int e = 0; e < 8; ++e) acc[e] = 0.0;
  for (int d = lane; d < DDIM; d += 64) {
    float xv = xr[d];
    const float4* wp = (const float4*)(Wg + (size_t)d * 8);
    float4 w0 = wp[0], w1 = wp[1];
    acc[0] += (double)xv * (double)w0.x;
    acc[1] += (double)xv * (double)w0.y;
    acc[2] += (double)xv * (double)w0.z;
    acc[3] += (double)xv * (double)w0.w;
    acc[4] += (double)xv * (double)w1.x;
    acc[5] += (double)xv * (double)w1.y;
    acc[6] += (double)xv * (double)w1.z;
    acc[7] += (double)xv * (double)w1.w;
  }
#pragma unroll
  for (int off = 32; off > 0; off >>= 1) {
#pragma unroll
    for (int e = 0; e < 8; ++e) acc[e] += __shfl_down(acc[e], off, 64);
  }
  if (lane == 0) {
    double mx = acc[0];
#pragma unroll
    for (int e = 1; e < 8; ++e) mx = acc[e] > mx ? acc[e] : mx;
    double ex[8], s = 0.0;
#pragma unroll
    for (int e = 0; e < 8; ++e) { ex[e] = exp(acc[e] - mx); s += ex[e]; }
    int best = 0;
#pragma unroll
    for (int e = 1; e < 8; ++e) if (acc[e] > acc[best]) best = e;  // first-max semantics
    double inv = 1.0 / s;
#pragma unroll
    for (int e = 0; e < 8; ++e) gate_out[(size_t)b * 8 + e] = (float)(ex[e] * inv);
    texp_out[b] = (float)best;
    tscore[b] = (float)(ex[best] * inv);
    expert_ws[b] = best;
    atomicAdd(&counts[best], 1);
  }
}

__global__ void init_kernel(int* __restrict__ counts) {
  if (threadIdx.x < NEXP) counts[threadIdx.x] = 0;
}

// single-thread scan: offsets, cursors, density, tile worklist
__global__ void scan_kernel(const int* __restrict__ counts, int* __restrict__ offsets,
                            int* __restrict__ cursors, int* __restrict__ tile_e,
                            int* __restrict__ tile_ms, int* __restrict__ total_tiles,
                            float* __restrict__ dens_out) {
  if (threadIdx.x == 0 && blockIdx.x == 0) {
    int off = 0, t = 0;
    for (int e = 0; e < NEXP; ++e) {
      offsets[e] = off;
      cursors[e] = off;
      dens_out[e] = (float)counts[e] / (float)BTOK;
      for (int ms = 0; ms < counts[e]; ms += 128) { tile_e[t] = e; tile_ms[t] = ms; ++t; }
      off += counts[e];
    }
    offsets[NEXP] = off;
    *total_tiles = t;
  }
}

__global__ __launch_bounds__(256) void scatter_kernel(
    const int* __restrict__ expert_ws, int* __restrict__ cursors,
    int* __restrict__ token_list) {
  int b = blockIdx.x * 256 + threadIdx.x;
  int e = expert_ws[b];
  int pos = atomicAdd(&cursors[e], 1);
  token_list[pos] = b;
}

// ---------------- conversion: x fp32 -> bf16 ----------------
__global__ __launch_bounds__(256) void cvt_x_kernel(const float* __restrict__ in,
                                                    unsigned short* __restrict__ out) {
  size_t i = ((size_t)blockIdx.x * 256 + threadIdx.x) * 8;
  float4 a = *(const float4*)(in + i);
  float4 b = *(const float4*)(in + i + 4);
  uint4 o = make_uint4(pack2(a.x, a.y), pack2(a.z, a.w), pack2(b.x, b.y), pack2(b.z, b.w));
  *(uint4*)(out + i) = o;
}

// ---------------- transpose + convert: in[z][R][C] fp32 -> out[z][C][R] bf16 ----------------
__global__ __launch_bounds__(256) void transpose_cvt_kernel(
    const float* __restrict__ in, unsigned short* __restrict__ out, int R, int C) {
  __shared__ unsigned int tile[64 * 33];  // 64x64 bf16 tile, 2 per word, pad 33
  const float* ine = in + (size_t)blockIdx.z * R * C;
  unsigned short* oute = out + (size_t)blockIdx.z * R * C;
  int r0 = blockIdx.y * 64, c0 = blockIdx.x * 64;
  int tid = threadIdx.x;
#pragma unroll
  for (int l = 0; l < 4; ++l) {
    int f = tid + 256 * l;          // 0..1023 float4 slots
    int r = f >> 4, c4 = f & 15;    // row, float4-col
    float4 v = *(const float4*)(ine + (size_t)(r0 + r) * C + c0 + c4 * 4);
    tile[r * 33 + c4 * 2]     = pack2(v.x, v.y);
    tile[r * 33 + c4 * 2 + 1] = pack2(v.z, v.w);
  }
  __syncthreads();
  const unsigned short* t16 = (const unsigned short*)tile;
#pragma unroll
  for (int l = 0; l < 4; ++l) {
    int f = tid + 256 * l;          // 0..1023
    int c = f >> 4, rq = f & 15;    // out-row (=col), r-quad
    unsigned short e0 = t16[((4 * rq + 0) * 33 + (c >> 1)) * 2 + (c & 1)];
    unsigned short e1 = t16[((4 * rq + 1) * 33 + (c >> 1)) * 2 + (c & 1)];
    unsigned short e2 = t16[((4 * rq + 2) * 33 + (c >> 1)) * 2 + (c & 1)];
    unsigned short e3 = t16[((4 * rq + 3) * 33 + (c >> 1)) * 2 + (c & 1)];
    uint2 o;
    o.x = (unsigned int)e0 | ((unsigned int)e1 << 16);
    o.y = (unsigned int)e2 | ((unsigned int)e3 << 16);
    *(uint2*)(oute + (size_t)(c0 + c) * R + r0 + rq * 4) = o;
  }
}

// ---------------- GEMM1: h = gelu(x_gathered @ W1[e] + b1[e]) -> bf16 ----------------
// m97 structure + XOR bank swizzle: LDS slot s of row r holds global chunk
// s ^ (r&3) ^ ((r>>2)&3). Readers: chunk q of row m is at slot q ^ (m&3) ^ ((m>>2)&3),
// which reduces to a per-lane constant (independent of i/j/wr/wc). 2-way banks = free.
__global__ __launch_bounds__(256, 4) void gemm1_kernel(
    const unsigned short* __restrict__ xbf, const unsigned short* __restrict__ W1t,
    const float* __restrict__ b1, const int* __restrict__ token_list,
    const int* __restrict__ offsets, const int* __restrict__ tile_e,
    const int* __restrict__ tile_ms, const int* __restrict__ total_tiles,
    unsigned short* __restrict__ hbuf) {
  __shared__ __align__(16) unsigned short ldsA[128 * 32];
  __shared__ __align__(16) unsigned short ldsB[128 * 32];

  int t = blockIdx.x;
  if (t >= *total_tiles) return;
  int e = tile_e[t], mstart = tile_ms[t];
  int base = offsets[e], endp = offsets[e + 1];
  int ntile = blockIdx.y;

  int tid = threadIdx.x;
  int lane = tid & 63, wid = tid >> 6;
  int wr = wid & 1, wc = wid >> 1;
  int quad = lane >> 4, l16 = lane & 15;

  int rowA = tid >> 2, slot = tid & 3;
  int sw = slot ^ (rowA & 3) ^ ((rowA >> 2) & 3);  // global chunk this lane stages
  int p0 = base + mstart + rowA;
  int p1 = p0 + 64;
  int tok0 = token_list[p0 < endp ? p0 : endp - 1];
  int tok1 = token_list[p1 < endp ? p1 : endp - 1];
  int offA0 = tok0 * DDIM + sw * 8;            // 32-bit offsets -> saddr+voffset form
  int offA1 = tok1 * DDIM + sw * 8;
  int offB0 = e * (HDIM * DDIM) + (ntile * 128 + rowA) * DDIM + sw * 8;
  int offB1 = offB0 + 64 * DDIM;
  unsigned short* la0 = &ldsA[tid * 8];
  unsigned short* la1 = &ldsA[2048 + tid * 8];
  unsigned short* lb0 = &ldsB[tid * 8];
  unsigned short* lb1 = &ldsB[2048 + tid * 8];

  int swq = (quad ^ (l16 & 3) ^ ((l16 >> 2) & 3)) * 8;  // read-side swizzled k-chunk

  f32x4 acc[4][4];
#pragma unroll
  for (int i = 0; i < 4; ++i)
#pragma unroll
    for (int j = 0; j < 4; ++j) acc[i][j] = (f32x4)0.0f;

  for (int k0 = 0; k0 < DDIM; k0 += 32) {
    gload16(xbf + offA0 + k0, la0);
    gload16(xbf + offA1 + k0, la1);
    gload16(W1t + offB0 + k0, lb0);
    gload16(W1t + offB1 + k0, lb1);
    __syncthreads();
    short8 af[4], bfr[4];
#pragma unroll
    for (int i = 0; i < 4; ++i)
      af[i] = *(const short8*)(&ldsA[(wr * 64 + 16 * i + l16) * 32 + swq]);
#pragma unroll
    for (int j = 0; j < 4; ++j)
      bfr[j] = *(const short8*)(&ldsB[(wc * 64 + 16 * j + l16) * 32 + swq]);
#pragma unroll
    for (int i = 0; i < 4; ++i)
#pragma unroll
      for (int j = 0; j < 4; ++j)
        acc[i][j] = __builtin_amdgcn_mfma_f32_16x16x32_bf16(af[i], bfr[j], acc[i][j], 0, 0, 0);
    __syncthreads();
  }

  const float* b1e = b1 + (size_t)e * HDIM + ntile * 128;
#pragma unroll
  for (int i = 0; i < 4; ++i) {
#pragma unroll
    for (int r = 0; r < 4; ++r) {
      int row = wr * 64 + 16 * i + quad * 4 + r;
      int p = base + mstart + row;
      if (p < endp) {
        size_t ob = (size_t)p * HDIM + ntile * 128;
#pragma unroll
        for (int j = 0; j < 4; ++j) {
          int col = wc * 64 + 16 * j + l16;
          float v = acc[i][j][r] + b1e[col];
          hbuf[ob + col] = (unsigned short)bf16r(gelu_fast(v));
        }
      }
    }
  }
}

// ---------------- GEMM2: out[tok] = (h @ W2[e] + b2[e]) * top_score ----------------
__global__ __launch_bounds__(256, 4) void gemm2_kernel(
    const unsigned short* __restrict__ hbuf, const unsigned short* __restrict__ W2t,
    const float* __restrict__ b2, const int* __restrict__ token_list,
    const int* __restrict__ offsets, const int* __restrict__ tile_e,
    const int* __restrict__ tile_ms, const int* __restrict__ total_tiles,
    const float* __restrict__ tscore, float* __restrict__ out) {
  __shared__ __align__(16) unsigned short ldsA[128 * 32];
  __shared__ __align__(16) unsigned short ldsB[128 * 32];

  int t = blockIdx.x;
  if (t >= *total_tiles) return;
  int e = tile_e[t], mstart = tile_ms[t];
  int base = offsets[e], endp = offsets[e + 1];
  int ntile = blockIdx.y;

  int tid = threadIdx.x;
  int lane = tid & 63, wid = tid >> 6;
  int wr = wid & 1, wc = wid >> 1;
  int quad = lane >> 4, l16 = lane & 15;

  int rowA = tid >> 2, slot = tid & 3;
  int sw = slot ^ (rowA & 3) ^ ((rowA >> 2) & 3);
  int p0 = base + mstart + rowA;
  int p1 = p0 + 64;
  int pe0 = p0 < endp ? p0 : endp - 1;
  int pe1 = p1 < endp ? p1 : endp - 1;
  int offA0 = pe0 * HDIM + sw * 8;
  int offA1 = pe1 * HDIM + sw * 8;
  int offB0 = e * (HDIM * DDIM) + (ntile * 128 + rowA) * HDIM + sw * 8;
  int offB1 = offB0 + 64 * HDIM;
  unsigned short* la0 = &ldsA[tid * 8];
  unsigned short* la1 = &ldsA[2048 + tid * 8];
  unsigned short* lb0 = &ldsB[tid * 8];
  unsigned short* lb1 = &ldsB[2048 + tid * 8];

  int swq = (quad ^ (l16 & 3) ^ ((l16 >> 2) & 3)) * 8;

  f32x4 acc[4][4];
#pragma unroll
  for (int i = 0; i < 4; ++i)
#pragma unroll
    for (int j = 0; j < 4; ++j) acc[i][j] = (f32x4)0.0f;

  for (int k0 = 0; k0 < HDIM; k0 += 32) {
    gload16(hbuf + offA0 + k0, la0);
    gload16(hbuf + offA1 + k0, la1);
    gload16(W2t + offB0 + k0, lb0);
    gload16(W2t + offB1 + k0, lb1);
    __syncthreads();
    short8 af[4], bfr[4];
#pragma unroll
    for (int i = 0; i < 4; ++i)
      af[i] = *(const short8*)(&ldsA[(wr * 64 + 16 * i + l16) * 32 + swq]);
#pragma unroll
    for (int j = 0; j < 4; ++j)
      bfr[j] = *(const short8*)(&ldsB[(wc * 64 + 16 * j + l16) * 32 + swq]);
#pragma unroll
    for (int i = 0; i < 4; ++i)
#pragma unroll
      for (int j = 0; j < 4; ++j)
        acc[i][j] = __builtin_amdgcn_mfma_f32_16x16x32_bf16(af[i], bfr[j], acc[i][j], 0, 0, 0);
    __syncthreads();
  }

  const float* b2e = b2 + (size_t)e * DDIM + ntile * 128;
#pragma unroll
  for (int i = 0; i < 4; ++i) {
#pragma unroll
    for (int r = 0; r < 4; ++r) {
      int row = wr * 64 + 16 * i + quad * 4 + r;
      int p = base + mstart + row;
      if (p < endp) {
        int tok = token_list[p];
        float ts = tscore[tok];
        size_t ob = (size_t)tok * DDIM + ntile * 128;
#pragma unroll
        for (int j = 0; j < 4; ++j) {
          int col = wc * 64 + 16 * j + l16;
          out[ob + col] = (acc[i][j][r] + b2e[col]) * ts;
        }
      }
    }
  }
}

extern "C" void kernel_launch(void* const* d_in, const int* in_sizes, int n_in,
                              void* d_out, int out_size, void* d_ws, size_t ws_size,
                              hipStream_t stream) {
  const float* x  = (const float*)d_in[0];
  const float* Wg = (const float*)d_in[1];
  const float* W1 = (const float*)d_in[2];
  const float* b1 = (const float*)d_in[3];
  const float* W2 = (const float*)d_in[4];
  const float* b2 = (const float*)d_in[5];

  float* out_main = (float*)d_out;
  float* gate_out = out_main + (size_t)BTOK * DDIM;
  float* texp_out = gate_out + (size_t)BTOK * NEXP;
  float* dens_out = texp_out + BTOK;

  char* w = (char*)d_ws;
  size_t off = 0;
  unsigned short* hbuf = (unsigned short*)(w + off); off += (size_t)BTOK * HDIM * 2;  // 134 MB
  unsigned short* xbf  = (unsigned short*)(w + off); off += (size_t)BTOK * DDIM * 2;  // 33.5 MB
  unsigned short* W1t  = (unsigned short*)(w + off); off += (size_t)NEXP * DDIM * HDIM * 2;  // 67 MB
  unsigned short* W2t  = (unsigned short*)(w + off); off += (size_t)NEXP * DDIM * HDIM * 2;  // 67 MB
  float* tscore     = (float*)(w + off); off += (size_t)BTOK * 4;
  int* expert_ws    = (int*)(w + off);   off += (size_t)BTOK * 4;
  int* token_list   = (int*)(w + off);   off += (size_t)BTOK * 4;
  int* counts       = (int*)(w + off);   off += 256;
  int* offsets      = (int*)(w + off);   off += 256;
  int* cursors      = (int*)(w + off);   off += 256;
  int* tile_e       = (int*)(w + off);   off += 1024;
  int* tile_ms      = (int*)(w + off);   off += 1024;
  int* total_tiles  = (int*)(w + off);   off += 256;

  hipLaunchKernelGGL(init_kernel, dim3(1), dim3(64), 0, stream, counts);
  hipLaunchKernelGGL(gate_kernel, dim3(BTOK / 4), dim3(256), 0, stream,
                     x, Wg, gate_out, texp_out, tscore, expert_ws, counts);
  hipLaunchKernelGGL(cvt_x_kernel, dim3(BTOK * DDIM / 2048), dim3(256), 0, stream, x, xbf);
  hipLaunchKernelGGL(transpose_cvt_kernel, dim3(HDIM / 64, DDIM / 64, NEXP), dim3(256), 0, stream,
                     W1, W1t, DDIM, HDIM);
  hipLaunchKernelGGL(transpose_cvt_kernel, dim3(DDIM / 64, HDIM / 64, NEXP), dim3(256), 0, stream,
                     W2, W2t, HDIM, DDIM);
  hipLaunchKernelGGL(scan_kernel, dim3(1), dim3(1), 0, stream,
                     counts, offsets, cursors, tile_e, tile_ms, total_tiles, dens_out);
  hipLaunchKernelGGL(scatter_kernel, dim3(BTOK / 256), dim3(256), 0, stream,
                     expert_ws, cursors, token_list);
  hipLaunchKernelGGL(gemm1_kernel, dim3(MAXT, HDIM / 128), dim3(256), 0, stream,
                     xbf, W1t, b1, token_list, offsets, tile_e, tile_ms, total_tiles, hbuf);
  hipLaunchKernelGGL(gemm2_kernel, dim3(MAXT, DDIM / 128), dim3(256), 0, stream,
                     hbuf, W2t, b2, token_list, offsets, tile_e, tile_ms, total_tiles, tscore, out_main);
}